// Round 2
// baseline (179.762 us; speedup 1.0000x reference)
//
#include <hip/hip_runtime.h>
#include <stdint.h>

#define SHAPE  512
#define DEPTH  9
#define NCELLS (SHAPE * SHAPE)

// Phase 0: sentinel init (replaces hipMemsetAsync — plain dispatch is
// unambiguously graph-capturable; the memset node was the prime suspect
// for the post-timing divergence).
__global__ void init_kernel(uint4* __restrict__ A, int nVec4) {
    int tid = blockIdx.x * blockDim.x + threadIdx.x;
    if (tid < nVec4)
        A[tid] = make_uint4(0xFFFFFFFFu, 0xFFFFFFFFu, 0xFFFFFFFFu, 0xFFFFFFFFu);
}

// Phase 1: concurrent top-9-min insertion per cell via atomicMin cascade.
// Slot s ends holding the (s+1)-th smallest point index of the cell, or
// 0xFFFFFFFF if the cell has <= s points. Deterministic under any thread
// interleaving: each slot op maps {content, v} -> {min, max}; multiset of
// values is conserved, so the quiescent state is the sorted top-DEPTH.
__global__ void cascade_kernel(const float4* __restrict__ pts,
                               unsigned* A, int strideMul,
                               int nTotal, int nPerB) {
    int tid = blockIdx.x * blockDim.x + threadIdx.x;
    if (tid >= nTotal) return;
    int b = tid / nPerB;
    int i = tid - b * nPerB;

    float4 p = pts[tid];
    if (p.x == 0.f && p.y == 0.f && p.z == 0.f && p.w == 0.f) return; // zero pts skipped

    float sx = p.x * (float)SHAPE;
    float sy = p.y * (float)SHAPE;
    int xi = (int)sx;              // truncation == reference astype(int32)
    int yi = (int)sy;
    int cell = xi * SHAPE + yi;
    if ((unsigned)cell >= (unsigned)NCELLS) return;  // safety (never for [0,1))

    unsigned v = (unsigned)i;
    unsigned* base = A + (size_t)(b * NCELLS + cell) * (DEPTH * strideMul);
#pragma unroll
    for (int s = 0; s < DEPTH; ++s) {
        unsigned old = atomicMin(base + s * strideMul, v);
        if (old == 0xFFFFFFFFu) break;   // landed in an empty slot
        v = (v > old) ? v : old;         // displaced max continues downstream
    }
    // values displaced past slot DEPTH-1 are dropped (reference overflow drop)
}

// Phase 2: one thread per (b, cell, slot). Reads staged index, gathers the
// point, writes the 4 output features (zeros for empty slots).
// In the fallback path A aliases `out` (index staged at the f==0 float of
// each slot); each thread reads only its own float4 before writing it.
__global__ void write_kernel(const float4* __restrict__ pts,
                             const unsigned* A, int strideMul,
                             float4* out, int nSlots, int nPerB) {
    int tid = blockIdx.x * blockDim.x + threadIdx.x;
    if (tid >= nSlots) return;

    unsigned idx = A[(size_t)tid * strideMul];
    float4 r = make_float4(0.f, 0.f, 0.f, 0.f);
    if (idx < (unsigned)nPerB) {
        int b = tid / (NCELLS * DEPTH);
        float4 p = pts[(size_t)b * nPerB + idx];
        float sx = p.x * (float)SHAPE;
        float sy = p.y * (float)SHAPE;
        r.x = sx - truncf(sx);
        r.y = sy - truncf(sy);
        r.z = p.z;
        r.w = p.w;
    }
    out[tid] = r;
}

extern "C" void kernel_launch(void* const* d_in, const int* in_sizes, int n_in,
                              void* d_out, int out_size, void* d_ws, size_t ws_size,
                              hipStream_t stream) {
    const float4* pts = (const float4*)d_in[0];

    const int B = 8;
    const int F = 4;
    int total  = in_sizes[0];            // 8*200000*4 = 6,400,000 floats
    int nPerB  = total / (B * F);        // 200,000
    int nPts   = B * nPerB;              // 1,600,000
    int nSlots = B * NCELLS * DEPTH;     // 18,874,368 (== out_size/4)
    size_t aBytes = (size_t)nSlots * sizeof(unsigned);  // 75.5 MB

    unsigned* A;
    int strideMul;
    int initVec4;
    if (ws_size >= aBytes) {
        A = (unsigned*)d_ws;             // compact staging in workspace
        strideMul = 1;
        initVec4 = nSlots / 4;           // 4,718,592 uint4
    } else {
        A = (unsigned*)d_out;            // stage at f==0 float of each slot
        strideMul = 4;
        initVec4 = out_size / 4;         // whole output as uint4 sentinels
    }

    const int bs = 256;
    init_kernel<<<(initVec4 + bs - 1) / bs, bs, 0, stream>>>((uint4*)A, initVec4);
    cascade_kernel<<<(nPts + bs - 1) / bs, bs, 0, stream>>>(
        pts, A, strideMul, nPts, nPerB);
    write_kernel<<<(nSlots + bs - 1) / bs, bs, 0, stream>>>(
        pts, A, strideMul, (float4*)d_out, nSlots, nPerB);
}

// Round 3
// 175.653 us; speedup vs baseline: 1.0234x; 1.0234x over previous
//
#include <hip/hip_runtime.h>
#include <stdint.h>

#define SHAPE   512
#define DEPTH   9
#define NCELLS  (SHAPE * SHAPE)
#define NB      8              // batches
#define RANGES  256            // cell ranges per batch
#define CR      (NCELLS / RANGES)   // 1024 cells per range
#define CRSHIFT 10
#define CAP     2048           // bucket capacity (mean occupancy 781, sigma ~28)
#define CAPSHIFT 11
#define CNT_STRIDE 16          // one counter per 64B line (kills line-level atomic contention)
#define SENT    0xFFFFFFFFu

// ---- fast path (workspace-bucketed, LDS cascade) ----

__global__ void zero_cnt_kernel(uint4* __restrict__ cnt4, int n4) {
    int tid = blockIdx.x * blockDim.x + threadIdx.x;
    if (tid < n4) cnt4[tid] = make_uint4(0u, 0u, 0u, 0u);
}

// Phase 1: append each nonzero point's index to its (batch, cell-range) bucket.
// Order within a bucket is irrelevant: phase 2's atomicMin cascade produces the
// sorted top-DEPTH indices regardless of insertion order.
__global__ void binning_kernel(const float4* __restrict__ pts,
                               unsigned* __restrict__ cnt,
                               unsigned* __restrict__ bucket,
                               int nPts, int nPerB) {
    int tid = blockIdx.x * blockDim.x + threadIdx.x;
    if (tid >= nPts) return;
    int b = tid / nPerB;
    int i = tid - b * nPerB;

    float4 p = pts[tid];
    if (p.x == 0.f && p.y == 0.f && p.z == 0.f && p.w == 0.f) return; // zero pts skipped

    int xi = (int)(p.x * (float)SHAPE);   // trunc == reference astype(int32)
    int yi = (int)(p.y * (float)SHAPE);
    unsigned cell = (unsigned)(xi * SHAPE + yi);
    if (cell >= (unsigned)NCELLS) return;             // safety (never for [0,1))

    int r = b * RANGES + (int)(cell >> CRSHIFT);
    unsigned pos = atomicAdd(&cnt[r * CNT_STRIDE], 1u);
    if (pos < CAP) bucket[((size_t)r << CAPSHIFT) + pos] = (unsigned)i;
}

// Phase 2: one block per (batch, range). LDS-resident top-9-min insertion per
// cell via atomicMin cascade (slot s ends holding the (s+1)-th smallest point
// index — deterministic under any interleaving), then coalesced output write.
__global__ __launch_bounds__(256) void group_kernel(const float4* __restrict__ pts,
                                                    const unsigned* __restrict__ cnt,
                                                    const unsigned* __restrict__ bucket,
                                                    float4* __restrict__ out,
                                                    int nPerB) {
    __shared__ unsigned slots[CR * DEPTH];            // 9216 u32 = 36 KB -> 4 blocks/CU
    int blk = blockIdx.x;
    int b = blk >> 8;                                 // RANGES = 256
    int r = blk & (RANGES - 1);

    for (int k = threadIdx.x; k < CR * DEPTH; k += 256) slots[k] = SENT;
    __syncthreads();

    unsigned n = cnt[blk * CNT_STRIDE];
    if (n > CAP) n = CAP;
    const unsigned* bk = bucket + ((size_t)blk << CAPSHIFT);
    const float4*   pb = pts + (size_t)b * nPerB;

    for (unsigned t = threadIdx.x; t < n; t += 256) {
        unsigned i = bk[t];
        float4 p = pb[i];
        int xi = (int)(p.x * (float)SHAPE);
        int yi = (int)(p.y * (float)SHAPE);
        unsigned c = (unsigned)(xi * SHAPE + yi) - ((unsigned)r << CRSHIFT);
        unsigned v = i;
        unsigned* s = &slots[c * DEPTH];
#pragma unroll
        for (int d = 0; d < DEPTH; ++d) {
            unsigned old = atomicMin(&s[d], v);
            if (old == SENT) break;                   // landed in an empty slot
            v = (v > old) ? v : old;                  // displaced max continues
        }
    }
    __syncthreads();

    // coalesced write: thread j -> float4 j of this range's output span
    float4* ob = out + ((size_t)b * NCELLS + ((size_t)r << CRSHIFT)) * DEPTH;
    for (int j = threadIdx.x; j < CR * DEPTH; j += 256) {
        unsigned idx = slots[j];
        float4 rv = make_float4(0.f, 0.f, 0.f, 0.f);
        if (idx != SENT) {
            float4 p = pb[idx];
            float sx = p.x * (float)SHAPE;
            float sy = p.y * (float)SHAPE;
            rv.x = sx - truncf(sx);
            rv.y = sy - truncf(sy);
            rv.z = p.z;
            rv.w = p.w;
        }
        ob[j] = rv;
    }
}

// ---- fallback path (stage in d_out, from round 1 — used only if ws too small) ----

__global__ void init_kernel(uint4* __restrict__ A, int nVec4) {
    int tid = blockIdx.x * blockDim.x + threadIdx.x;
    if (tid < nVec4) A[tid] = make_uint4(SENT, SENT, SENT, SENT);
}

__global__ void cascade_kernel(const float4* __restrict__ pts,
                               unsigned* A, int nTotal, int nPerB) {
    int tid = blockIdx.x * blockDim.x + threadIdx.x;
    if (tid >= nTotal) return;
    int b = tid / nPerB;
    int i = tid - b * nPerB;
    float4 p = pts[tid];
    if (p.x == 0.f && p.y == 0.f && p.z == 0.f && p.w == 0.f) return;
    int xi = (int)(p.x * (float)SHAPE), yi = (int)(p.y * (float)SHAPE);
    int cell = xi * SHAPE + yi;
    if ((unsigned)cell >= (unsigned)NCELLS) return;
    unsigned v = (unsigned)i;
    unsigned* base = A + (size_t)(b * NCELLS + cell) * (DEPTH * 4);
#pragma unroll
    for (int s = 0; s < DEPTH; ++s) {
        unsigned old = atomicMin(base + s * 4, v);
        if (old == SENT) break;
        v = (v > old) ? v : old;
    }
}

__global__ void write_kernel(const float4* __restrict__ pts,
                             const unsigned* A, float4* out, int nSlots, int nPerB) {
    int tid = blockIdx.x * blockDim.x + threadIdx.x;
    if (tid >= nSlots) return;
    unsigned idx = A[(size_t)tid * 4];
    float4 r = make_float4(0.f, 0.f, 0.f, 0.f);
    if (idx < (unsigned)nPerB) {
        int b = tid / (NCELLS * DEPTH);
        float4 p = pts[(size_t)b * nPerB + idx];
        float sx = p.x * (float)SHAPE, sy = p.y * (float)SHAPE;
        r.x = sx - truncf(sx); r.y = sy - truncf(sy);
        r.z = p.z; r.w = p.w;
    }
    out[tid] = r;
}

extern "C" void kernel_launch(void* const* d_in, const int* in_sizes, int n_in,
                              void* d_out, int out_size, void* d_ws, size_t ws_size,
                              hipStream_t stream) {
    const float4* pts = (const float4*)d_in[0];

    int total  = in_sizes[0];                 // 8*200000*4
    int nPerB  = total / (NB * 4);            // 200,000
    int nPts   = NB * nPerB;                  // 1,600,000
    const int bs = 256;

    size_t cntBytes    = (size_t)NB * RANGES * CNT_STRIDE * sizeof(unsigned); // 128 KB
    size_t bucketBytes = (size_t)NB * RANGES * CAP * sizeof(unsigned);        // 16 MB

    if (ws_size >= cntBytes + bucketBytes) {
        unsigned* cnt    = (unsigned*)d_ws;
        unsigned* bucket = (unsigned*)((char*)d_ws + cntBytes);

        int n4 = (int)(cntBytes / 16);
        zero_cnt_kernel<<<(n4 + bs - 1) / bs, bs, 0, stream>>>((uint4*)cnt, n4);
        binning_kernel<<<(nPts + bs - 1) / bs, bs, 0, stream>>>(
            pts, cnt, bucket, nPts, nPerB);
        group_kernel<<<NB * RANGES, bs, 0, stream>>>(
            pts, cnt, bucket, (float4*)d_out, nPerB);
    } else {
        // fallback: stage indices at the f==0 float of each slot inside d_out
        int nSlots = NB * NCELLS * DEPTH;
        unsigned* A = (unsigned*)d_out;
        int initVec4 = out_size / 4;
        init_kernel<<<(initVec4 + bs - 1) / bs, bs, 0, stream>>>((uint4*)A, initVec4);
        cascade_kernel<<<(nPts + bs - 1) / bs, bs, 0, stream>>>(pts, A, nPts, nPerB);
        write_kernel<<<(nSlots + bs - 1) / bs, bs, 0, stream>>>(
            pts, A, (float4*)d_out, nSlots, nPerB);
    }
}

// Round 4
// 151.901 us; speedup vs baseline: 1.1834x; 1.1564x over previous
//
#include <hip/hip_runtime.h>
#include <stdint.h>

#define SHAPE    512
#define DEPTH    9
#define NCELLS   (SHAPE * SHAPE)
#define NB       8                 // batches
#define RANGES   512               // cell ranges per batch
#define CR       (NCELLS / RANGES) // 512 cells per range
#define CRSHIFT  9
#define CAP      1024              // bucket capacity (mean 391, sigma ~20 -> 32 sigma)
#define CAPSHIFT 10
#define CNT_STRIDE 16              // one counter per 64B line
#define SENT     0xFFFFFFFFu

// ---- fast path ----

__global__ void zero_cnt_kernel(uint4* __restrict__ cnt4, int n4) {
    int tid = blockIdx.x * blockDim.x + threadIdx.x;
    if (tid < n4) cnt4[tid] = make_uint4(0u, 0u, 0u, 0u);
}

// Phase 1: append each nonzero point's VALUE (float4) and index to its
// (batch, cell-range) bucket. Bucket order is irrelevant: the cascade key
// orders by original index exactly.
__global__ void binning_kernel(const float4* __restrict__ pts,
                               unsigned* __restrict__ cnt,
                               float4* __restrict__ bktP,
                               unsigned* __restrict__ bktI,
                               int nPerB) {
    int i = blockIdx.x * blockDim.x + threadIdx.x;
    if (i >= nPerB) return;
    int b = blockIdx.y;

    float4 p = pts[(size_t)b * nPerB + i];
    if (p.x == 0.f && p.y == 0.f && p.z == 0.f && p.w == 0.f) return; // zero pts skipped

    int xi = (int)(p.x * (float)SHAPE);   // trunc == reference astype(int32)
    int yi = (int)(p.y * (float)SHAPE);
    unsigned cell = (unsigned)(xi * SHAPE + yi);
    if (cell >= (unsigned)NCELLS) return;             // never for [0,1)

    int r = b * RANGES + (int)(cell >> CRSHIFT);
    unsigned pos = atomicAdd(&cnt[r * CNT_STRIDE], 1u);
    if (pos < CAP) {
        size_t e = ((size_t)r << CAPSHIFT) + pos;
        bktP[e] = p;
        bktI[e] = (unsigned)i;
    }
}

// Phase 2: one block per (batch, range). Points staged in LDS; top-9-min
// insertion per cell via atomicMin cascade on key = (index<<10)|bucket_pos
// (primary order = original index, unique; low bits = free pointer into the
// staged LDS copy). Emit loop is 100% LDS-fed -> pure streaming stores.
__global__ __launch_bounds__(256) void group_kernel(const unsigned* __restrict__ cnt,
                                                    const float4* __restrict__ bktP,
                                                    const unsigned* __restrict__ bktI,
                                                    float4* __restrict__ out) {
    __shared__ unsigned slots[CR * DEPTH];   // 4608 u32 = 18 KB
    __shared__ float4   staged[CAP];         // 16 KB
    int r = blockIdx.x;                      // range within batch
    int b = blockIdx.y;
    int blk = b * RANGES + r;

    uint4* s4 = (uint4*)slots;
    for (int k = threadIdx.x; k < (CR * DEPTH) / 4; k += 256)
        s4[k] = make_uint4(SENT, SENT, SENT, SENT);
    __syncthreads();

    unsigned n = cnt[blk * CNT_STRIDE];
    if (n > CAP) n = CAP;
    size_t base = (size_t)blk << CAPSHIFT;

    for (unsigned t = threadIdx.x; t < n; t += 256) {
        float4 p = bktP[base + t];
        unsigned i = bktI[base + t];
        staged[t] = p;
        int xi = (int)(p.x * (float)SHAPE);
        int yi = (int)(p.y * (float)SHAPE);
        unsigned c = (unsigned)(xi * SHAPE + yi) - ((unsigned)r << CRSHIFT);
        unsigned v = (i << CAPSHIFT) | t;
        unsigned* s = &slots[c * DEPTH];
#pragma unroll
        for (int d = 0; d < DEPTH; ++d) {
            unsigned old = atomicMin(&s[d], v);
            if (old == SENT) break;                   // empty slot claimed
            v = (v > old) ? v : old;                  // displaced max continues
        }
    }
    __syncthreads();

    // emit: thread j -> float4 j of this range's contiguous output span
    float4* ob = out + ((size_t)b * NCELLS + ((size_t)r << CRSHIFT)) * DEPTH;
    for (int j = threadIdx.x; j < CR * DEPTH; j += 256) {
        unsigned key = slots[j];
        float4 rv = make_float4(0.f, 0.f, 0.f, 0.f);
        if (key != SENT) {
            float4 p = staged[key & (CAP - 1)];
            float sx = p.x * (float)SHAPE;
            float sy = p.y * (float)SHAPE;
            rv.x = sx - truncf(sx);
            rv.y = sy - truncf(sy);
            rv.z = p.z;
            rv.w = p.w;
        }
        ob[j] = rv;
    }
}

// ---- fallback path (stage indices inside d_out; used only if ws too small
//      or per-batch point count exceeds the 18-bit key budget) ----

__global__ void init_kernel(uint4* __restrict__ A, int nVec4) {
    int tid = blockIdx.x * blockDim.x + threadIdx.x;
    if (tid < nVec4) A[tid] = make_uint4(SENT, SENT, SENT, SENT);
}

__global__ void cascade_kernel(const float4* __restrict__ pts,
                               unsigned* A, int nTotal, int nPerB) {
    int tid = blockIdx.x * blockDim.x + threadIdx.x;
    if (tid >= nTotal) return;
    int b = tid / nPerB;
    int i = tid - b * nPerB;
    float4 p = pts[tid];
    if (p.x == 0.f && p.y == 0.f && p.z == 0.f && p.w == 0.f) return;
    int xi = (int)(p.x * (float)SHAPE), yi = (int)(p.y * (float)SHAPE);
    int cell = xi * SHAPE + yi;
    if ((unsigned)cell >= (unsigned)NCELLS) return;
    unsigned v = (unsigned)i;
    unsigned* base = A + (size_t)(b * NCELLS + cell) * (DEPTH * 4);
#pragma unroll
    for (int s = 0; s < DEPTH; ++s) {
        unsigned old = atomicMin(base + s * 4, v);
        if (old == SENT) break;
        v = (v > old) ? v : old;
    }
}

__global__ void write_kernel(const float4* __restrict__ pts,
                             const unsigned* A, float4* out, int nSlots, int nPerB) {
    int tid = blockIdx.x * blockDim.x + threadIdx.x;
    if (tid >= nSlots) return;
    unsigned idx = A[(size_t)tid * 4];
    float4 r = make_float4(0.f, 0.f, 0.f, 0.f);
    if (idx < (unsigned)nPerB) {
        int b = tid / (NCELLS * DEPTH);
        float4 p = pts[(size_t)b * nPerB + idx];
        float sx = p.x * (float)SHAPE, sy = p.y * (float)SHAPE;
        r.x = sx - truncf(sx); r.y = sy - truncf(sy);
        r.z = p.z; r.w = p.w;
    }
    out[tid] = r;
}

extern "C" void kernel_launch(void* const* d_in, const int* in_sizes, int n_in,
                              void* d_out, int out_size, void* d_ws, size_t ws_size,
                              hipStream_t stream) {
    const float4* pts = (const float4*)d_in[0];

    int total = in_sizes[0];               // 8*200000*4
    int nPerB = total / (NB * 4);          // 200,000
    const int bs = 256;

    int nBuckets = NB * RANGES;                                        // 4096
    size_t cntBytes = (size_t)nBuckets * CNT_STRIDE * sizeof(unsigned); // 256 KB
    size_t pBytes   = (size_t)nBuckets * CAP * sizeof(float4);          // 64 MB
    size_t iBytes   = (size_t)nBuckets * CAP * sizeof(unsigned);        // 16 MB

    bool fast = (ws_size >= cntBytes + pBytes + iBytes) && (nPerB <= (1 << 18));
    if (fast) {
        unsigned* cnt  = (unsigned*)d_ws;
        float4*   bktP = (float4*)((char*)d_ws + cntBytes);
        unsigned* bktI = (unsigned*)((char*)d_ws + cntBytes + pBytes);

        int n4 = (int)(cntBytes / 16);
        zero_cnt_kernel<<<(n4 + bs - 1) / bs, bs, 0, stream>>>((uint4*)cnt, n4);

        dim3 bgrid((nPerB + bs - 1) / bs, NB);
        binning_kernel<<<bgrid, bs, 0, stream>>>(pts, cnt, bktP, bktI, nPerB);

        dim3 ggrid(RANGES, NB);
        group_kernel<<<ggrid, bs, 0, stream>>>(cnt, bktP, bktI, (float4*)d_out);
    } else {
        int nPts   = NB * nPerB;
        int nSlots = NB * NCELLS * DEPTH;
        unsigned* A = (unsigned*)d_out;
        int initVec4 = out_size / 4;
        init_kernel<<<(initVec4 + bs - 1) / bs, bs, 0, stream>>>((uint4*)A, initVec4);
        cascade_kernel<<<(nPts + bs - 1) / bs, bs, 0, stream>>>(pts, A, nPts, nPerB);
        write_kernel<<<(nSlots + bs - 1) / bs, bs, 0, stream>>>(
            pts, A, (float4*)d_out, nSlots, nPerB);
    }
}

// Round 6
// 110.891 us; speedup vs baseline: 1.6211x; 1.3698x over previous
//
#include <hip/hip_runtime.h>
#include <stdint.h>

#define SHAPE    512
#define DEPTH    9
#define NCELLS   (SHAPE * SHAPE)
#define NB       8                 // batches
#define RANGES   512               // cell ranges per batch
#define CR       (NCELLS / RANGES) // 512 cells per range
#define CRSHIFT  9
#define CAP      1024              // bucket capacity (mean 391, ~32 sigma headroom)
#define CAPSHIFT 10
#define NCHUNK   32                // point chunks per batch (counting-sort granularity)
#define SENT     0xFFFFFFFFu

typedef float f32x4 __attribute__((ext_vector_type(4)));   // native vector for nontemporal store

// ---- fast path: counting-sort binning + LDS cascade group ----

// Pass A: per (chunk, batch) histogram over the 512 cell-ranges.
__global__ __launch_bounds__(256) void hist_kernel(const float4* __restrict__ pts,
                                                   unsigned* __restrict__ hist,
                                                   int nPerB, int chSz) {
    __shared__ unsigned lh[RANGES];
    int c = blockIdx.x, b = blockIdx.y;
    for (int r = threadIdx.x; r < RANGES; r += 256) lh[r] = 0;
    __syncthreads();

    int i0 = c * chSz;
    int i1 = i0 + chSz; if (i1 > nPerB) i1 = nPerB;
    const float4* pb = pts + (size_t)b * nPerB;
    for (int i = i0 + threadIdx.x; i < i1; i += 256) {
        float4 p = pb[i];
        if (p.x == 0.f && p.y == 0.f && p.z == 0.f && p.w == 0.f) continue;
        int xi = (int)(p.x * (float)SHAPE);   // trunc == reference astype(int32)
        int yi = (int)(p.y * (float)SHAPE);
        unsigned cell = (unsigned)(xi * SHAPE + yi);
        if (cell >= (unsigned)NCELLS) continue;
        atomicAdd(&lh[cell >> CRSHIFT], 1u);
    }
    __syncthreads();
    for (int r = threadIdx.x; r < RANGES; r += 256)
        hist[((size_t)(b * RANGES + r)) * NCHUNK + c] = lh[r];
}

// Pass B: one thread per (batch, range): prefix over chunks -> exact segment
// start positions; also emits the bucket total (no zero-init pass needed).
__global__ void prefix_kernel(const unsigned* __restrict__ hist,
                              unsigned* __restrict__ offs,
                              unsigned* __restrict__ cnt) {
    int tid = blockIdx.x * blockDim.x + threadIdx.x;   // (b*RANGES + r)
    if (tid >= NB * RANGES) return;
    size_t base = (size_t)tid * NCHUNK;
    unsigned run = (unsigned)tid << CAPSHIFT;          // bucket base position
    for (int c = 0; c < NCHUNK; ++c) {
        offs[base + c] = run;
        run += hist[base + c];
    }
    cnt[tid] = run - ((unsigned)tid << CAPSHIFT);      // total points in bucket
}

// Pass C: scatter points + indices into their exact bucket segments.
// Each (chunk, range) stream is contiguous (~12 entries = 195 B) -> near-
// full-line writes, no global atomics, no write-amplification blowup.
__global__ __launch_bounds__(256) void scatter_kernel(const float4* __restrict__ pts,
                                                      const unsigned* __restrict__ offs,
                                                      float4* __restrict__ bktP,
                                                      unsigned* __restrict__ bktI,
                                                      int nPerB, int chSz) {
    __shared__ unsigned cur[RANGES];
    int c = blockIdx.x, b = blockIdx.y;
    for (int r = threadIdx.x; r < RANGES; r += 256)
        cur[r] = offs[((size_t)(b * RANGES + r)) * NCHUNK + c];
    __syncthreads();

    int i0 = c * chSz;
    int i1 = i0 + chSz; if (i1 > nPerB) i1 = nPerB;
    const float4* pb = pts + (size_t)b * nPerB;
    for (int i = i0 + threadIdx.x; i < i1; i += 256) {
        float4 p = pb[i];
        if (p.x == 0.f && p.y == 0.f && p.z == 0.f && p.w == 0.f) continue;
        int xi = (int)(p.x * (float)SHAPE);
        int yi = (int)(p.y * (float)SHAPE);
        unsigned cell = (unsigned)(xi * SHAPE + yi);
        if (cell >= (unsigned)NCELLS) continue;
        unsigned r = cell >> CRSHIFT;
        unsigned pos = atomicAdd(&cur[r], 1u);
        unsigned end = ((unsigned)(b * RANGES + r) + 1u) << CAPSHIFT;
        if (pos < end) {                               // overflow points dropped
            bktP[pos] = p;
            bktI[pos] = (unsigned)i;
        }
    }
}

// Phase 2: one block per (batch, range). Points staged in LDS; top-9-min
// insertion per cell via atomicMin cascade on key = (index<<10)|bucket_pos
// (primary order = original index, unique -> deterministic output regardless
// of bucket arrangement). Emit loop is 100% LDS-fed streaming stores.
__global__ __launch_bounds__(256) void group_kernel(const unsigned* __restrict__ cnt,
                                                    const float4* __restrict__ bktP,
                                                    const unsigned* __restrict__ bktI,
                                                    float4* __restrict__ out) {
    __shared__ unsigned slots[CR * DEPTH];   // 4608 u32 = 18 KB
    __shared__ float4   staged[CAP];         // 16 KB
    int r = blockIdx.x;
    int b = blockIdx.y;
    int blk = b * RANGES + r;

    uint4* s4 = (uint4*)slots;
    for (int k = threadIdx.x; k < (CR * DEPTH) / 4; k += 256)
        s4[k] = make_uint4(SENT, SENT, SENT, SENT);
    __syncthreads();

    unsigned n = cnt[blk];
    if (n > CAP) n = CAP;
    size_t base = (size_t)blk << CAPSHIFT;

    for (unsigned t = threadIdx.x; t < n; t += 256) {
        float4 p = bktP[base + t];
        unsigned i = bktI[base + t];
        staged[t] = p;
        int xi = (int)(p.x * (float)SHAPE);
        int yi = (int)(p.y * (float)SHAPE);
        unsigned c = (unsigned)(xi * SHAPE + yi) - ((unsigned)r << CRSHIFT);
        unsigned v = (i << CAPSHIFT) | t;
        unsigned* s = &slots[c * DEPTH];
#pragma unroll
        for (int d = 0; d < DEPTH; ++d) {
            unsigned old = atomicMin(&s[d], v);
            if (old == SENT) break;                   // empty slot claimed
            v = (v > old) ? v : old;                  // displaced max continues
        }
    }
    __syncthreads();

    // emit: thread j -> float4 j of this range's contiguous output span
    float4* ob = out + ((size_t)b * NCELLS + ((size_t)r << CRSHIFT)) * DEPTH;
    for (int j = threadIdx.x; j < CR * DEPTH; j += 256) {
        unsigned key = slots[j];
        f32x4 rv = (f32x4){0.f, 0.f, 0.f, 0.f};
        if (key != SENT) {
            float4 p = staged[key & (CAP - 1)];
            float sx = p.x * (float)SHAPE;
            float sy = p.y * (float)SHAPE;
            rv.x = sx - truncf(sx);
            rv.y = sy - truncf(sy);
            rv.z = p.z;
            rv.w = p.w;
        }
        __builtin_nontemporal_store(rv, (f32x4*)&ob[j]);  // pure streaming output
    }
}

// ---- fallback path (stage indices inside d_out; used only if ws too small
//      or per-batch point count exceeds the 18-bit key budget) ----

__global__ void init_kernel(uint4* __restrict__ A, int nVec4) {
    int tid = blockIdx.x * blockDim.x + threadIdx.x;
    if (tid < nVec4) A[tid] = make_uint4(SENT, SENT, SENT, SENT);
}

__global__ void cascade_kernel(const float4* __restrict__ pts,
                               unsigned* A, int nTotal, int nPerB) {
    int tid = blockIdx.x * blockDim.x + threadIdx.x;
    if (tid >= nTotal) return;
    int b = tid / nPerB;
    int i = tid - b * nPerB;
    float4 p = pts[tid];
    if (p.x == 0.f && p.y == 0.f && p.z == 0.f && p.w == 0.f) return;
    int xi = (int)(p.x * (float)SHAPE), yi = (int)(p.y * (float)SHAPE);
    int cell = xi * SHAPE + yi;
    if ((unsigned)cell >= (unsigned)NCELLS) return;
    unsigned v = (unsigned)i;
    unsigned* base = A + (size_t)(b * NCELLS + cell) * (DEPTH * 4);
#pragma unroll
    for (int s = 0; s < DEPTH; ++s) {
        unsigned old = atomicMin(base + s * 4, v);
        if (old == SENT) break;
        v = (v > old) ? v : old;
    }
}

__global__ void write_kernel(const float4* __restrict__ pts,
                             const unsigned* A, float4* out, int nSlots, int nPerB) {
    int tid = blockIdx.x * blockDim.x + threadIdx.x;
    if (tid >= nSlots) return;
    unsigned idx = A[(size_t)tid * 4];
    float4 r = make_float4(0.f, 0.f, 0.f, 0.f);
    if (idx < (unsigned)nPerB) {
        int b = tid / (NCELLS * DEPTH);
        float4 p = pts[(size_t)b * nPerB + idx];
        float sx = p.x * (float)SHAPE, sy = p.y * (float)SHAPE;
        r.x = sx - truncf(sx); r.y = sy - truncf(sy);
        r.z = p.z; r.w = p.w;
    }
    out[tid] = r;
}

extern "C" void kernel_launch(void* const* d_in, const int* in_sizes, int n_in,
                              void* d_out, int out_size, void* d_ws, size_t ws_size,
                              hipStream_t stream) {
    const float4* pts = (const float4*)d_in[0];

    int total = in_sizes[0];               // 8*200000*4
    int nPerB = total / (NB * 4);          // 200,000
    const int bs = 256;

    int nBuckets = NB * RANGES;                                         // 4096
    size_t pBytes    = (size_t)nBuckets * CAP * sizeof(float4);         // 64 MB (16B-aligned first)
    size_t iBytes    = (size_t)nBuckets * CAP * sizeof(unsigned);       // 16 MB
    size_t histBytes = (size_t)nBuckets * NCHUNK * sizeof(unsigned);    // 512 KB
    size_t offsBytes = histBytes;                                       // 512 KB
    size_t cntBytes  = (size_t)nBuckets * sizeof(unsigned);             // 16 KB
    size_t need = pBytes + iBytes + histBytes + offsBytes + cntBytes;

    bool fast = (ws_size >= need) && (nPerB <= (1 << 18));
    if (fast) {
        char* w = (char*)d_ws;
        float4*   bktP = (float4*)w;                  w += pBytes;
        unsigned* bktI = (unsigned*)w;                w += iBytes;
        unsigned* hist = (unsigned*)w;                w += histBytes;
        unsigned* offs = (unsigned*)w;                w += offsBytes;
        unsigned* cnt  = (unsigned*)w;

        int chSz = (nPerB + NCHUNK - 1) / NCHUNK;     // 6250

        dim3 cgrid(NCHUNK, NB);
        hist_kernel<<<cgrid, bs, 0, stream>>>(pts, hist, nPerB, chSz);
        prefix_kernel<<<(nBuckets + bs - 1) / bs, bs, 0, stream>>>(hist, offs, cnt);
        scatter_kernel<<<cgrid, bs, 0, stream>>>(pts, offs, bktP, bktI, nPerB, chSz);

        dim3 ggrid(RANGES, NB);
        group_kernel<<<ggrid, bs, 0, stream>>>(cnt, bktP, bktI, (float4*)d_out);
    } else {
        int nPts   = NB * nPerB;
        int nSlots = NB * NCELLS * DEPTH;
        unsigned* A = (unsigned*)d_out;
        int initVec4 = out_size / 4;
        init_kernel<<<(initVec4 + bs - 1) / bs, bs, 0, stream>>>((uint4*)A, initVec4);
        cascade_kernel<<<(nPts + bs - 1) / bs, bs, 0, stream>>>(pts, A, nPts, nPerB);
        write_kernel<<<(nSlots + bs - 1) / bs, bs, 0, stream>>>(
            pts, A, (float4*)d_out, nSlots, nPerB);
    }
}